// Round 4
// baseline (292.912 us; speedup 1.0000x reference)
//
#include <hip/hip_runtime.h>
#include <hip/hip_bf16.h>

#define BB   131072
#define CC   16
#define DIN  256
#define DH   1024
#define DOUT 256
#define TM   64    // tokens per tile
#define NHB  32    // hidden blocks of 32
#define NB   512   // bucketing blocks (BB/NB = 256 tokens each)

typedef __attribute__((ext_vector_type(8))) short bf16x8;
typedef __attribute__((ext_vector_type(4))) short short4v;
typedef __attribute__((ext_vector_type(4))) float f32x4;
typedef __attribute__((ext_vector_type(4))) float float4v;

__device__ inline unsigned short f2b(float f) {
  union { float f; unsigned u; } v; v.f = f;
  unsigned u = v.u;
  return (unsigned short)((u + 0x7fffu + ((u >> 16) & 1u)) >> 16);  // RNE
}

__device__ inline void gload_lds16(const void* g, void* l) {
  __builtin_amdgcn_global_load_lds(
      (const __attribute__((address_space(1))) void*)g,
      (__attribute__((address_space(3))) void*)l, 16, 0, 0);
}

#define MFMA16(a, b, c) __builtin_amdgcn_mfma_f32_16x16x32_bf16((a), (b), (c), 0, 0, 0)

// ---------------- bucketing (contention-free counting sort) ----------------
__global__ void hist_k(const int* __restrict__ cat, int* __restrict__ blockhist) {
  __shared__ int h[CC];
  const int tid = threadIdx.x;
  if (tid < CC) h[tid] = 0;
  __syncthreads();
  const int i = blockIdx.x * 256 + tid;
  atomicAdd(&h[cat[i]], 1);
  __syncthreads();
  if (tid < CC) blockhist[blockIdx.x * CC + tid] = h[tid];
}

__global__ void offsets2_k(const int* __restrict__ blockhist,
                           int* __restrict__ counts, int* __restrict__ padoff,
                           int* __restrict__ base) {
  __shared__ int part[CC][64];
  __shared__ int pref[CC][64];
  __shared__ int scnt[CC];
  __shared__ int spad[CC + 1];
  const int tid = threadIdx.x;       // 1024 threads
  const int c = tid >> 6;
  const int g = tid & 63;
  int h[8];
  int s = 0;
#pragma unroll
  for (int i = 0; i < 8; i++) {
    h[i] = blockhist[(g * 8 + i) * CC + c];
    s += h[i];
  }
  part[c][g] = s;
  __syncthreads();
  if (g == 0) {
    int r = 0;
    for (int j = 0; j < 64; j++) { pref[c][j] = r; r += part[c][j]; }
    scnt[c] = r;
  }
  __syncthreads();
  if (tid == 0) {
    int acc = 0;
    for (int c2 = 0; c2 < CC; c2++) {
      spad[c2] = acc;
      padoff[c2] = acc;
      counts[c2] = scnt[c2];
      acc += ((scnt[c2] + TM - 1) / TM) * TM;
    }
    spad[CC] = acc;
    padoff[CC] = acc;
  }
  __syncthreads();
  int run = spad[c] + pref[c][g];
#pragma unroll
  for (int i = 0; i < 8; i++) {
    base[(g * 8 + i) * CC + c] = run;
    run += h[i];
  }
}

__global__ void scatter2_k(const int* __restrict__ cat, const int* __restrict__ base,
                           int* __restrict__ idx) {
  __shared__ int cur[CC];
  const int tid = threadIdx.x;
  if (tid < CC) cur[tid] = base[blockIdx.x * CC + tid];
  __syncthreads();
  const int i = blockIdx.x * 256 + tid;
  const int c = cat[i];
  const int pos = atomicAdd(&cur[c], 1);
  idx[pos] = i;
}

// ---------------- weight conversion (f32 -> bf16, transposed [c][n][k]) ----------------
// W1 src: [c][k=256][n=1024] -> dst rows (c*1024+n)*512 bytes, chunk byte (k*2)^((n&7)<<4)
__global__ void conv_w1_k(const float* __restrict__ W1, short* __restrict__ w1b) {
  int t = blockIdx.x * blockDim.x + threadIdx.x;
  int n = t & 1023;
  int j = (t >> 10) & 31;
  int c = t >> 15;
  const float* src = W1 + (size_t)c * 256 * 1024;
  bf16x8 o;
#pragma unroll
  for (int i = 0; i < 8; i++)
    o[i] = (short)f2b(src[(size_t)(j * 8 + i) * 1024 + n]);
  char* dst = (char*)w1b + (size_t)(c * 1024 + n) * 512 + ((j * 16) ^ ((n & 7) << 4));
  *(bf16x8*)dst = o;
}

// W2 src: [c][k=1024][n=256] -> dst rows (c*256+n)*2048 bytes, byte k*2 (no swizzle;
// LDS rows are 64B at HBLK=32 so reads sit at the bank floor already)
__global__ void conv_w2_k(const float* __restrict__ W2, short* __restrict__ w2b) {
  int t = blockIdx.x * blockDim.x + threadIdx.x;
  int n = t & 255;
  int j = (t >> 8) & 127;
  int c = t >> 15;
  const float* src = W2 + (size_t)c * 1024 * 256;
  bf16x8 o;
#pragma unroll
  for (int i = 0; i < 8; i++)
    o[i] = (short)f2b(src[(size_t)(j * 8 + i) * 256 + n]);
  char* dst = (char*)w2b + (size_t)(c * 256 + n) * 2048 + j * 16;
  *(bf16x8*)dst = o;
}

// ---------------- fused routed MLP ----------------
// 512 thr (8 waves = wt(4 token groups of 16) x wh(2)). Tile = 64 tokens.
// 32 hidden blocks of 32: L1 [64t x 256k]x[32n] -> relu -> hs ; L2 acc += [64t x 32k]x[256n]
// A = weights, B = activations, D = [n][token].
// LDS: w1 dbuf 2x16K @0 | w2 dbuf 2x16K @32K | hs 4K @64K | toks @68K | b1s | b2s  (~73.3K)
#define W2OFF  32768
#define HSOFF  65536
#define TKOFF  69632
#define B1OFF  69888
#define B2OFF  73984
#define SMSZ   75008

__launch_bounds__(512, 4)
__global__ void mlp_k(const float* __restrict__ x,
                      const float* __restrict__ b1,
                      const float* __restrict__ b2,
                      const short* __restrict__ w1b,
                      const short* __restrict__ w2b,
                      const int* __restrict__ idx,
                      const int* __restrict__ padoff,
                      const int* __restrict__ counts,
                      float* __restrict__ out) {
  __shared__ __align__(16) char sm[SMSZ];

  const int bhw = blockIdx.x;
  const int wg = (bhw & 7) * 258 + (bhw >> 3);   // XCD-chunked swizzle, 2064 = 8*258
  const int p = wg * TM;
  const int total = padoff[CC];
  if (p >= total) return;
  int c = 0;
  while (padoff[c + 1] <= p) c++;
  const int cnt = counts[c];
  const int start = p - padoff[c];

  const int tid  = threadIdx.x;
  const int lane = tid & 63;
  const int w    = tid >> 6;   // 0..7
  const int wt   = w >> 1;     // 0..3 token group (16 each)
  const int wh   = w & 1;      // L1: 16-n half; L2: 128-out half
  const int lrow = lane & 15;
  const int lgrp = lane >> 4;

  char*  hsb   = sm + HSOFF;
  int*   toksp = (int*)(sm + TKOFF);
  float* b1s   = (float*)(sm + B1OFF);
  float* b2s   = (float*)(sm + B2OFF);

  // ---- prologue: gather x (f32->bf16, swizzled) into sm[0..32K), toks, biases ----
  {
    const int r = tid >> 3;      // 0..63
    const int q = tid & 7;       // 32-float chunk
    const int pos = start + r;
    int tok = (pos < cnt) ? idx[p + r] : -1;
    if (q == 0) toksp[r] = tok;
    const int swz = (r & 7) << 4;
    char* rowb = sm + r * 512;
    if (tok >= 0) {
      const float4v* src = (const float4v*)(x + (size_t)tok * DIN) + q * 8;
#pragma unroll
      for (int m = 0; m < 4; m++) {
        float4v v0 = src[2 * m];
        float4v v1 = src[2 * m + 1];
        bf16x8 o;
        o[0] = (short)f2b(v0[0]); o[1] = (short)f2b(v0[1]);
        o[2] = (short)f2b(v0[2]); o[3] = (short)f2b(v0[3]);
        o[4] = (short)f2b(v1[0]); o[5] = (short)f2b(v1[1]);
        o[6] = (short)f2b(v1[2]); o[7] = (short)f2b(v1[3]);
        *(bf16x8*)(rowb + ((q * 64 + m * 16) ^ swz)) = o;
      }
    } else {
      bf16x8 z = {0, 0, 0, 0, 0, 0, 0, 0};
#pragma unroll
      for (int m = 0; m < 4; m++)
        *(bf16x8*)(rowb + ((q * 64 + m * 16) ^ swz)) = z;
    }
    if (tid < 256) ((f32x4*)b1s)[tid] = ((const f32x4*)(b1 + (size_t)c * DH))[tid];
    if (tid < 64)  ((f32x4*)b2s)[tid] = ((const f32x4*)(b2 + (size_t)c * DOUT))[tid];
  }
  __syncthreads();

  // ---- x fragments to registers: xf[ks] (B-operand: col=token) ----
  bf16x8 xf[8];
  {
    const int r = wt * 16 + lrow;
    const int swz = (r & 7) << 4;
#pragma unroll
    for (int ks = 0; ks < 8; ks++)
      xf[ks] = *(const bf16x8*)(sm + r * 512 + ((ks * 64 + lgrp * 16) ^ swz));
  }
  __syncthreads();   // xs region free -> weight buffers

  const char* w1g = (const char*)w1b + (size_t)c * 1024 * 512;
  const char* w2g = (const char*)w2b + (size_t)c * 256 * 2048;

  auto stage1 = [&](int i) {
    const char* src = w1g + (size_t)i * 16384;
    char* dst = sm + (i & 1) * 16384;
#pragma unroll
    for (int j = 0; j < 2; j++) {
      int chunk = (w * 2 + j) * 1024;
      gload_lds16(src + chunk + lane * 16, dst + chunk);
    }
  };
  auto stage2 = [&](int i) {
    char* dst = sm + W2OFF + (i & 1) * 16384;
#pragma unroll
    for (int j = 0; j < 2; j++) {
      int o = (w * 2 + j) * 1024 + lane * 16;
      int n = o >> 6;          // 64 B per n-row
      int q = o & 63;
      gload_lds16(w2g + (size_t)n * 2048 + i * 64 + q, dst + (w * 2 + j) * 1024);
    }
  };

  stage1(0);
  stage2(0);
  asm volatile("s_waitcnt vmcnt(0)" ::: "memory");
  __syncthreads();

  f32x4 acc2[8];
#pragma unroll
  for (int ni = 0; ni < 8; ni++)
    acc2[ni] = (f32x4){0.f, 0.f, 0.f, 0.f};

  const int rtok = wt * 16 + lrow;               // this lane's token slot

  for (int hb = 0; hb < NHB; hb++) {
    const char* w1c = sm + (hb & 1) * 16384;
    const char* w2c = sm + W2OFF + (hb & 1) * 16384;

    // ===== region A: L1 (8 MFMA) + bias/relu/pack -> hs =====
    f32x4 acc1 = (f32x4){0.f, 0.f, 0.f, 0.f};
    const int n1 = wh * 16 + lrow;
    const int sw1 = (n1 & 7) << 4;
#pragma unroll
    for (int ks = 0; ks < 8; ks++) {
      bf16x8 a1 = *(const bf16x8*)(w1c + n1 * 512 + ((ks * 64 + lgrp * 16) ^ sw1));
      acc1 = MFMA16(a1, xf[ks], acc1);
    }
    {
      const int n0 = wh * 16 + lgrp * 4;
      f32x4 bv = *(const f32x4*)(b1s + hb * 32 + n0);
      short4v h;
#pragma unroll
      for (int jj = 0; jj < 4; jj++)
        h[jj] = (short)f2b(fmaxf(acc1[jj] + bv[jj], 0.0f));
      *(short4v*)(hsb + rtok * 64 + wh * 32 + lgrp * 8) = h;
    }
    // w2[hb] landed (2 loads, issued a full region earlier); hs visible after barrier
    asm volatile("s_waitcnt vmcnt(0) lgkmcnt(0)" ::: "memory");
    __builtin_amdgcn_s_barrier();

    // ===== region B: stage hb+1, L2 (8 MFMA) =====
    if (hb < NHB - 1) { stage1(hb + 1); stage2(hb + 1); }

    bf16x8 hf = *(const bf16x8*)(hsb + rtok * 64 + lgrp * 16);
#pragma unroll
    for (int ni = 0; ni < 8; ni++) {
      const int n = wh * 128 + ni * 16 + lrow;
      bf16x8 a2 = *(const bf16x8*)(w2c + n * 64 + lgrp * 16);
      acc2[ni] = MFMA16(a2, hf, acc2[ni]);
    }
    // w1[hb+1] done (w2's 2 loads may remain in flight); hs reads drained before rewrite
    asm volatile("s_waitcnt vmcnt(2) lgkmcnt(0)" ::: "memory");
    __builtin_amdgcn_s_barrier();
  }

  // ---- epilogue: + b2, vectorized scatter ----
  const int tok = toksp[rtok];
  if (tok >= 0) {
#pragma unroll
    for (int ni = 0; ni < 8; ni++) {
      const int n0 = wh * 128 + ni * 16 + lgrp * 4;
      f32x4 bv = *(const f32x4*)(b2s + n0);
      f32x4 v = acc2[ni] + bv;
      *(f32x4*)(out + (size_t)tok * DOUT + n0) = v;
    }
  }
}

extern "C" void kernel_launch(void* const* d_in, const int* in_sizes, int n_in,
                              void* d_out, int out_size, void* d_ws, size_t ws_size,
                              hipStream_t stream) {
  (void)in_sizes; (void)n_in; (void)out_size; (void)ws_size;
  const float* x   = (const float*)d_in[0];
  const int*   cat = (const int*)d_in[1];
  const float* W1  = (const float*)d_in[2];
  const float* b1  = (const float*)d_in[3];
  const float* W2  = (const float*)d_in[4];
  const float* b2  = (const float*)d_in[5];
  float* out = (float*)d_out;

  char* ws = (char*)d_ws;
  int* counts    = (int*)(ws);
  int* padoff    = (int*)(ws + 128);
  int* blockhist = (int*)(ws + 4096);
  int* base      = (int*)(ws + 65536);
  int* idx       = (int*)(ws + 131072);
  short* w1b     = (short*)(ws + (1 << 20));
  short* w2b     = (short*)(ws + (1 << 20) + 8388608);

  hist_k<<<NB, 256, 0, stream>>>(cat, blockhist);
  offsets2_k<<<1, 1024, 0, stream>>>(blockhist, counts, padoff, base);
  scatter2_k<<<NB, 256, 0, stream>>>(cat, base, idx);
  conv_w1_k<<<2048, 256, 0, stream>>>(W1, w1b);
  conv_w2_k<<<2048, 256, 0, stream>>>(W2, w2b);

  const int ntiles = BB / TM + CC;   // 2064 = 8 * 258 (swizzle assumes this)
  mlp_k<<<ntiles, 512, 0, stream>>>(x, b1, b2, w1b, w2b, idx, padoff, counts, out);
}

// Round 5
// 236.575 us; speedup vs baseline: 1.2381x; 1.2381x over previous
//
#include <hip/hip_runtime.h>
#include <hip/hip_bf16.h>

#define BB   131072
#define CC   16
#define DIN  256
#define DH   1024
#define DOUT 256
#define TM   64    // tokens per tile
#define NHB  32    // hidden blocks of 32
#define NB   512   // bucketing blocks (BB/NB = 256 tokens each)

typedef __attribute__((ext_vector_type(8))) short bf16x8;
typedef __attribute__((ext_vector_type(4))) short short4v;
typedef __attribute__((ext_vector_type(4))) float f32x4;
typedef __attribute__((ext_vector_type(4))) float float4v;

__device__ inline unsigned short f2b(float f) {
  union { float f; unsigned u; } v; v.f = f;
  unsigned u = v.u;
  return (unsigned short)((u + 0x7fffu + ((u >> 16) & 1u)) >> 16);  // RNE
}

__device__ inline void gload_lds16(const void* g, void* l) {
  __builtin_amdgcn_global_load_lds(
      (const __attribute__((address_space(1))) void*)g,
      (__attribute__((address_space(3))) void*)l, 16, 0, 0);
}

#define MFMA16(a, b, c) __builtin_amdgcn_mfma_f32_16x16x32_bf16((a), (b), (c), 0, 0, 0)

// ---------------- bucketing (contention-free counting sort) ----------------
__global__ void hist_k(const int* __restrict__ cat, int* __restrict__ blockhist) {
  __shared__ int h[CC];
  const int tid = threadIdx.x;
  if (tid < CC) h[tid] = 0;
  __syncthreads();
  const int i = blockIdx.x * 256 + tid;
  atomicAdd(&h[cat[i]], 1);
  __syncthreads();
  if (tid < CC) blockhist[blockIdx.x * CC + tid] = h[tid];
}

__global__ void offsets2_k(const int* __restrict__ blockhist,
                           int* __restrict__ counts, int* __restrict__ padoff,
                           int* __restrict__ base) {
  __shared__ int part[CC][64];
  __shared__ int pref[CC][64];
  __shared__ int scnt[CC];
  __shared__ int spad[CC + 1];
  const int tid = threadIdx.x;       // 1024 threads
  const int c = tid >> 6;
  const int g = tid & 63;
  int h[8];
  int s = 0;
#pragma unroll
  for (int i = 0; i < 8; i++) {
    h[i] = blockhist[(g * 8 + i) * CC + c];
    s += h[i];
  }
  part[c][g] = s;
  __syncthreads();
  if (g == 0) {
    int r = 0;
    for (int j = 0; j < 64; j++) { pref[c][j] = r; r += part[c][j]; }
    scnt[c] = r;
  }
  __syncthreads();
  if (tid == 0) {
    int acc = 0;
    for (int c2 = 0; c2 < CC; c2++) {
      spad[c2] = acc;
      padoff[c2] = acc;
      counts[c2] = scnt[c2];
      acc += ((scnt[c2] + TM - 1) / TM) * TM;
    }
    spad[CC] = acc;
    padoff[CC] = acc;
  }
  __syncthreads();
  int run = spad[c] + pref[c][g];
#pragma unroll
  for (int i = 0; i < 8; i++) {
    base[(g * 8 + i) * CC + c] = run;
    run += h[i];
  }
}

__global__ void scatter2_k(const int* __restrict__ cat, const int* __restrict__ base,
                           int* __restrict__ idx) {
  __shared__ int cur[CC];
  const int tid = threadIdx.x;
  if (tid < CC) cur[tid] = base[blockIdx.x * CC + tid];
  __syncthreads();
  const int i = blockIdx.x * 256 + tid;
  const int c = cat[i];
  const int pos = atomicAdd(&cur[c], 1);
  idx[pos] = i;
}

// -------- weight conversion: f32 -> bf16 in MFMA A-fragment order --------
// Fragment map (verified rounds 1-4): for a 16(row)x32(k) A-tile, lane =
// (row&15) + 16*((k&31)>>3), byte j = (k&7)*2. Tiles stored [tile][lane][16B].
//
// W1: per category [hb=32][nt=2][ks=8][64 lanes][16B]  (16 KB per hb)
//   row = n (hidden), k = din. hb = n>>5, nt = (n>>4)&1, ks = k>>5.
__global__ void conv_w1_k(const float* __restrict__ W1, short* __restrict__ w1b) {
  int t = blockIdx.x * blockDim.x + threadIdx.x;   // 524288
  int n  = t & 1023;
  int j8 = (t >> 10) & 31;   // k-chunk of 8: k = j8*8+i
  int c  = t >> 15;
  const float* src = W1 + (size_t)c * DIN * DH;
  bf16x8 o;
#pragma unroll
  for (int i = 0; i < 8; i++)
    o[i] = (short)f2b(src[(size_t)(j8 * 8 + i) * DH + n]);
  char* dst = (char*)w1b + (size_t)c * 524288
            + (n >> 5) * 16384 + ((n >> 4) & 1) * 8192 + (j8 >> 2) * 1024
            + ((n & 15) + 16 * (j8 & 3)) * 16;
  *(bf16x8*)dst = o;
}

// W2: per category [hb=32][nt=16][64 lanes][16B]  (16 KB per hb)
//   row = n (out), k = hidden. hb = k>>5, nt = n>>4.
__global__ void conv_w2_k(const float* __restrict__ W2, short* __restrict__ w2b) {
  int t = blockIdx.x * blockDim.x + threadIdx.x;   // 524288
  int n  = t & 255;
  int j8 = (t >> 8) & 127;   // k-chunk of 8
  int c  = t >> 15;
  const float* src = W2 + (size_t)c * DH * DOUT;
  bf16x8 o;
#pragma unroll
  for (int i = 0; i < 8; i++)
    o[i] = (short)f2b(src[(size_t)(j8 * 8 + i) * DOUT + n]);
  char* dst = (char*)w2b + (size_t)c * 524288
            + (j8 >> 2) * 16384 + (n >> 4) * 1024
            + ((n & 15) + 16 * (j8 & 3)) * 16;
  *(bf16x8*)dst = o;
}

// ---------------- fused routed MLP ----------------
// 512 thr (8 waves = wt(4 token tiles of 16) x wh(2)). Tile = 64 tokens.
// All LDS tiles in fragment order [tile][lane][16B] -> conflict-free b128.
// LDS: w1 dbuf 2x16K @0 | w2 dbuf 2x16K @32K | hs 4K @64K | toks | b1s | b2s
#define W2OFF  32768
#define HSOFF  65536
#define TKOFF  69632
#define B1OFF  69888
#define B2OFF  73984
#define SMSZ   75008

__launch_bounds__(512, 4)
__global__ void mlp_k(const float* __restrict__ x,
                      const float* __restrict__ b1,
                      const float* __restrict__ b2,
                      const short* __restrict__ w1b,
                      const short* __restrict__ w2b,
                      const int* __restrict__ idx,
                      const int* __restrict__ padoff,
                      const int* __restrict__ counts,
                      float* __restrict__ out) {
  __shared__ __align__(16) char sm[SMSZ];

  const int bhw = blockIdx.x;
  const int wg = (bhw & 7) * 258 + (bhw >> 3);   // XCD-chunked swizzle, 2064 = 8*258
  const int p = wg * TM;
  const int total = padoff[CC];
  if (p >= total) return;
  int c = 0;
  while (padoff[c + 1] <= p) c++;
  const int cnt = counts[c];
  const int start = p - padoff[c];

  const int tid  = threadIdx.x;
  const int lane = tid & 63;
  const int w    = tid >> 6;   // 0..7
  const int wt   = w >> 1;     // 0..3 token tile (16 tokens)
  const int wh   = w & 1;      // L1: 16-n half of 32; L2: 128-out half
  const int lrow = lane & 15;
  const int lgrp = lane >> 4;

  char*  hsb   = sm + HSOFF;
  int*   toksp = (int*)(sm + TKOFF);
  float* b1s   = (float*)(sm + B1OFF);
  float* b2s   = (float*)(sm + B2OFF);

  // ---- prologue: gather x, f32->bf16, store in B-fragment order ----
  // xs frag-order: [tj=4][ks=8][64 lanes][16B] over sm[0..32K)
  {
    const int r = tid >> 3;      // 0..63 token slot
    const int q = tid & 7;       // ks (32-k chunk)
    const int pos = start + r;
    int tok = (pos < cnt) ? idx[p + r] : -1;
    if (q == 0) toksp[r] = tok;
    char* tilebase = sm + ((r >> 4) * 8 + q) * 1024 + (r & 15) * 16;
    if (tok >= 0) {
      const float4v* src = (const float4v*)(x + (size_t)tok * DIN) + q * 8;
#pragma unroll
      for (int m = 0; m < 4; m++) {       // lgrp position
        float4v v0 = src[2 * m];
        float4v v1 = src[2 * m + 1];
        bf16x8 o;
        o[0] = (short)f2b(v0[0]); o[1] = (short)f2b(v0[1]);
        o[2] = (short)f2b(v0[2]); o[3] = (short)f2b(v0[3]);
        o[4] = (short)f2b(v1[0]); o[5] = (short)f2b(v1[1]);
        o[6] = (short)f2b(v1[2]); o[7] = (short)f2b(v1[3]);
        *(bf16x8*)(tilebase + m * 256) = o;
      }
    } else {
      bf16x8 z = {0, 0, 0, 0, 0, 0, 0, 0};
#pragma unroll
      for (int m = 0; m < 4; m++)
        *(bf16x8*)(tilebase + m * 256) = z;
    }
    if (tid < 256) ((f32x4*)b1s)[tid] = ((const f32x4*)(b1 + (size_t)c * DH))[tid];
    if (tid < 64)  ((f32x4*)b2s)[tid] = ((const f32x4*)(b2 + (size_t)c * DOUT))[tid];
  }
  __syncthreads();

  // ---- x fragments to registers ----
  bf16x8 xf[8];
#pragma unroll
  for (int ks = 0; ks < 8; ks++)
    xf[ks] = *(const bf16x8*)(sm + (wt * 8 + ks) * 1024 + lane * 16);
  __syncthreads();   // all reads done; xs region becomes weight buffers

  const char* w1g = (const char*)w1b + (size_t)c * 524288;
  const char* w2g = (const char*)w2b + (size_t)c * 524288;

  auto stage1 = [&](int i) {
    const char* src = w1g + (size_t)i * 16384;
    char* dst = sm + (i & 1) * 16384;
#pragma unroll
    for (int j = 0; j < 2; j++) {
      int chunk = (w * 2 + j) * 1024;
      gload_lds16(src + chunk + lane * 16, dst + chunk);
    }
  };
  auto stage2 = [&](int i) {
    const char* src = w2g + (size_t)i * 16384;
    char* dst = sm + W2OFF + (i & 1) * 16384;
#pragma unroll
    for (int j = 0; j < 2; j++) {
      int chunk = (w * 2 + j) * 1024;
      gload_lds16(src + chunk + lane * 16, dst + chunk);
    }
  };

  stage1(0);
  stage2(0);
  asm volatile("s_waitcnt vmcnt(0)" ::: "memory");
  __syncthreads();

  f32x4 acc2[8];
#pragma unroll
  for (int ni = 0; ni < 8; ni++)
    acc2[ni] = (f32x4){0.f, 0.f, 0.f, 0.f};

  const int rtok = wt * 16 + lrow;               // this lane's token slot
  // hs write address (D-frag -> B-frag order), constant per thread:
  char* hswr = hsb + wt * 1024 + (lrow + 16 * (wh * 2 + (lgrp >> 1))) * 16 + (lgrp & 1) * 8;

  for (int hb = 0; hb < NHB; hb++) {
    const char* w1c = sm + (hb & 1) * 16384 + wh * 8192;
    const char* w2c = sm + W2OFF + (hb & 1) * 16384 + wh * 8192;

    // ===== region A: issue next stage, L1 (8 MFMA, 2 chains), relu -> hs =====
    if (hb < NHB - 1) { stage1(hb + 1); stage2(hb + 1); }

    f32x4 acc1a = (f32x4){0.f, 0.f, 0.f, 0.f};
    f32x4 acc1b = (f32x4){0.f, 0.f, 0.f, 0.f};
#pragma unroll
    for (int ks = 0; ks < 8; ks += 2) {
      bf16x8 a0 = *(const bf16x8*)(w1c + ks * 1024 + lane * 16);
      bf16x8 a1 = *(const bf16x8*)(w1c + (ks + 1) * 1024 + lane * 16);
      acc1a = MFMA16(a0, xf[ks], acc1a);
      acc1b = MFMA16(a1, xf[ks + 1], acc1b);
    }
    {
      const int n0 = wh * 16 + lgrp * 4;
      f32x4 bv = *(const f32x4*)(b1s + hb * 32 + n0);
      short4v h;
#pragma unroll
      for (int jj = 0; jj < 4; jj++)
        h[jj] = (short)f2b(fmaxf(acc1a[jj] + acc1b[jj] + bv[jj], 0.0f));
      *(short4v*)hswr = h;
    }
    // w2[hb] landed (oldest beyond the 4 just-issued); hs visible after barrier
    asm volatile("s_waitcnt vmcnt(4) lgkmcnt(0)" ::: "memory");
    __builtin_amdgcn_s_barrier();

    // ===== region B: L2 (8 MFMA, independent accs) =====
    bf16x8 hf = *(const bf16x8*)(hsb + wt * 1024 + lane * 16);
#pragma unroll
    for (int ni = 0; ni < 8; ni++) {
      bf16x8 a2 = *(const bf16x8*)(w2c + ni * 1024 + lane * 16);
      acc2[ni] = MFMA16(a2, hf, acc2[ni]);
    }
    // w1[hb+1] done (w2[hb+1]'s 2 loads may stay in flight); hs reads drained
    asm volatile("s_waitcnt vmcnt(2) lgkmcnt(0)" ::: "memory");
    __builtin_amdgcn_s_barrier();
  }

  // ---- epilogue: + b2, vectorized scatter ----
  const int tok = toksp[rtok];
  if (tok >= 0) {
#pragma unroll
    for (int ni = 0; ni < 8; ni++) {
      const int n0 = (wh * 8 + ni) * 16 + lgrp * 4;
      f32x4 bv = *(const f32x4*)(b2s + n0);
      f32x4 v = acc2[ni] + bv;
      *(f32x4*)(out + (size_t)tok * DOUT + n0) = v;
    }
  }
}

extern "C" void kernel_launch(void* const* d_in, const int* in_sizes, int n_in,
                              void* d_out, int out_size, void* d_ws, size_t ws_size,
                              hipStream_t stream) {
  (void)in_sizes; (void)n_in; (void)out_size; (void)ws_size;
  const float* x   = (const float*)d_in[0];
  const int*   cat = (const int*)d_in[1];
  const float* W1  = (const float*)d_in[2];
  const float* b1  = (const float*)d_in[3];
  const float* W2  = (const float*)d_in[4];
  const float* b2  = (const float*)d_in[5];
  float* out = (float*)d_out;

  char* ws = (char*)d_ws;
  int* counts    = (int*)(ws);
  int* padoff    = (int*)(ws + 128);
  int* blockhist = (int*)(ws + 4096);
  int* base      = (int*)(ws + 65536);
  int* idx       = (int*)(ws + 131072);
  short* w1b     = (short*)(ws + (1 << 20));
  short* w2b     = (short*)(ws + (1 << 20) + 8388608);

  hist_k<<<NB, 256, 0, stream>>>(cat, blockhist);
  offsets2_k<<<1, 1024, 0, stream>>>(blockhist, counts, padoff, base);
  scatter2_k<<<NB, 256, 0, stream>>>(cat, base, idx);
  conv_w1_k<<<2048, 256, 0, stream>>>(W1, w1b);
  conv_w2_k<<<2048, 256, 0, stream>>>(W2, w2b);

  const int ntiles = BB / TM + CC;   // 2064 = 8 * 258 (swizzle assumes this)
  mlp_k<<<ntiles, 512, 0, stream>>>(x, b1, b2, w1b, w2b, idx, padoff, counts, out);
}